// Round 12
// baseline (871.825 us; speedup 1.0000x reference)
//
#include <hip/hip_runtime.h>

#define NN 10000
#define BB 32
#define EE 40000
#define HH 4
#define DD 10
#define TT 10
#define FS 12          // padded feat row stride (48 B, 16-B aligned)
#define JJ 8           // padded edge slots per node
#define SLOTS 9        // 8 edge slots + self
#define NEG 0.2f

#define NB   (NN*BB)          // 320000
#define NBT  (NN*BB*TT)       // 3200000
#define NBF  (NN*BB*FS)       // 3840000 padded feat elems
#define CHUNKS (2*SLOTS*96)   // 1728 16-B chunks per block (2 nodes)

// ---------------- extract mu/sigma + regression heads ----------------
__global__ void extract_kernel(const float* __restrict__ x,
                               const float* __restrict__ wmu, const float* __restrict__ bmu,
                               const float* __restrict__ wsg, const float* __restrict__ bsg,
                               float* __restrict__ mu, float* __restrict__ sg,
                               float* __restrict__ regmu, float* __restrict__ regsg) {
    int i = blockIdx.x * blockDim.x + threadIdx.x;   // over N*B
    if (i >= NB) return;
    int n = i / BB, b = i % BB;
    float smu = 0.f, ssg = 0.f;
    float muv[TT], sgv[TT];
#pragma unroll
    for (int t = 0; t < TT; t++) {
        size_t xi = (((size_t)t * NN + n) * BB + b) * 3;
        float m = x[xi], s = x[xi + 1];
        muv[t] = m; sgv[t] = s;
        smu += m * wmu[t];
        ssg += s * wsg[t];
    }
#pragma unroll
    for (int t = 0; t < TT; t++) {
        mu[(size_t)i * FS + t] = muv[t];
        sg[(size_t)i * FS + t] = sgv[t];
    }
    regmu[i] = smu + bmu[0];
    regsg[i] = ssg + bsg[0];
}

// ---------------- CSR build ----------------
__global__ void deg_kernel(const int* __restrict__ dst, int* __restrict__ deg) {
    int e = blockIdx.x * blockDim.x + threadIdx.x;
    if (e < EE) atomicAdd(&deg[dst[e]], 1);
}

__global__ void csr8init_kernel(int* __restrict__ c8a, int* __restrict__ c8b) {
    int i = blockIdx.x * blockDim.x + threadIdx.x;   // NN*JJ
    if (i < NN * JJ) { int n = i >> 3; c8a[i] = n; c8b[i] = n; }
}

__global__ void scan_kernel(const int* __restrict__ deg, int* __restrict__ off) {
    __shared__ int sm[1024];
    __shared__ int carry_s;
    if (threadIdx.x == 0) { carry_s = 0; off[0] = 0; }
    __syncthreads();
    for (int base = 0; base < NN; base += 1024) {
        int i = base + (int)threadIdx.x;
        int v = (i < NN) ? deg[i] : 0;
        sm[threadIdx.x] = v;
        __syncthreads();
        for (int s = 1; s < 1024; s <<= 1) {
            int t = (threadIdx.x >= (unsigned)s) ? sm[threadIdx.x - s] : 0;
            __syncthreads();
            sm[threadIdx.x] += t;
            __syncthreads();
        }
        if (i < NN) off[i + 1] = carry_s + sm[threadIdx.x];
        __syncthreads();
        if (threadIdx.x == 0) carry_s += sm[1023];
        __syncthreads();
    }
}

__global__ void fill_kernel(const int* __restrict__ src, const int* __restrict__ dst,
                            const int* __restrict__ off, int* __restrict__ cursor,
                            int* __restrict__ csr_src, int* __restrict__ csrP) {
    int e = blockIdx.x * blockDim.x + threadIdx.x;
    if (e < EE) {
        int d = dst[e];
        int p = atomicAdd(&cursor[d], 1);
        int s = src[e];
        csr_src[off[d] + p] = s;
        if (p < JJ) csrP[d * JJ + p] = s;
    }
}

// ---------------- precompute vl/vr for all 8 GATs ----------------
// vbuf layout: 8 slots of [vl(H*T=40) | vr(40)];
__global__ void vpre_kernel(const float* __restrict__ fc0, const float* __restrict__ al0, const float* __restrict__ ar0,
                            const float* __restrict__ fc1, const float* __restrict__ al1, const float* __restrict__ ar1,
                            const float* __restrict__ fc2, const float* __restrict__ al2, const float* __restrict__ ar2,
                            const float* __restrict__ fc3, const float* __restrict__ al3, const float* __restrict__ ar3,
                            float* __restrict__ vbuf) {
    int j = threadIdx.x;                 // 0..319
    if (j >= 320) return;
    int g = j / 40, r = j % 40;
    int h = r / 10, t = r % 10;
    int which = g & 3, layer = g >> 2;
    const float* fc; const float* al; const float* ar;
    if (which == 0)      { fc = fc0; al = al0; ar = ar0; }
    else if (which == 1) { fc = fc1; al = al1; ar = ar1; }
    else if (which == 2) { fc = fc2; al = al2; ar = ar2; }
    else                 { fc = fc3; al = al3; ar = ar3; }
    fc += layer * (HH * DD * TT);
    al += layer * (HH * DD);
    ar += layer * (HH * DD);
    float vl = 0.f, vr = 0.f;
#pragma unroll
    for (int d = 0; d < DD; d++) {
        float w = fc[(h * DD + d) * TT + t];
        vl += al[h * DD + d] * w;
        vr += ar[h * DD + d] * w;
    }
    vbuf[g * 80 + r] = vl;
    vbuf[g * 80 + 40 + r] = vr;
}

// ---------------- gatlds: async-DMA-staged GAT pass ----------------
// r12: r11's VGPR=48 proved the compiler re-serializes any register-held
// load burst (it never keeps >~2 rows in flight -> per-wave MLP ~1-2, which
// latency-models to the observed ~85 us/pass wall; r1's 2.15 TB/s shows the
// miss path itself has 6x headroom). Fix: __builtin_amdgcn_global_load_lds
// (no VGPR results, nothing for the scheduler to serialize). Block = 2 nodes:
// issue all (8 edge slots + self) x 32 b row-blocks = 1728 independent 16-B
// chunks to LDS (27.6 KB), one barrier (vmcnt drain), compute from LDS.
// Serial memory depth per BLOCK: csrP -> row burst = 2 rounds for 16 waves
// of work. Sentinel slots (csrP init = self) fetch dup lines -> MSHR-merged.
// deg>8 overflow (~2% nodes) falls back to direct global loads.
struct GatCfg {
    const float* f; const float* W; const float* v;
    const int* off; const int* csr; const int* csrP; const int* deg;
    float* g; float* stats;
};
struct GatCfg4 { GatCfg c[4]; };

#define LOAD_ROW(dst, q)                                        \
    {                                                           \
        float4 _r0 = *(const float4*)(q);                       \
        float4 _r1 = *(const float4*)((q) + 4);                 \
        float2 _r2 = *(const float2*)((q) + 8);                 \
        dst[0]=_r0.x; dst[1]=_r0.y; dst[2]=_r0.z; dst[3]=_r0.w; \
        dst[4]=_r1.x; dst[5]=_r1.y; dst[6]=_r1.z; dst[7]=_r1.w; \
        dst[8]=_r2.x; dst[9]=_r2.y;                             \
    }

template <bool STATS>
__global__ void __launch_bounds__(256)
gatlds_kernel(GatCfg4 cfgs) {
    const GatCfg cfg = cfgs.c[blockIdx.y];
    __shared__ float rows[2 * SLOTS * 32 * FS];   // 6912 floats = 27648 B
    __shared__ float sW[HH * DD * TT];            // 400
    __shared__ float sv[2 * HH * TT];             // 80
    int tid = threadIdx.x;
    for (int k = tid; k < HH * DD * TT; k += 256) sW[k] = cfg.W[k];
    if (tid < 2 * HH * TT) sv[tid] = cfg.v[tid];

    const float* __restrict__ f = cfg.f;
    int n0 = blockIdx.x * 2;

    // ---- async prefetch: 1728 chunks, all independent, zero VGPR results --
    // chunk c -> byte offset c*16 in rows[]; layout (g, slot, b, part):
    // ((g*9+slot)*32 + b)*48 + part*16, matching compute-phase indexing.
#pragma unroll
    for (int it = 0; it < 7; ++it) {
        int c = it * 256 + tid;
        if (c < CHUNKS) {                      // 1728 = 27 waves: wave-uniform
            int rblk = c / 96;                 // 0..17
            int o    = c - rblk * 96;          // 0..95
            int g    = rblk / SLOTS;
            int slot = rblk - g * SLOTS;
            int n    = n0 + g;
            int src  = (slot < JJ) ? cfg.csrP[n * JJ + slot] : n;
            int b    = o / 3, part = o - b * 3;
            const float* gp = f + (size_t)(src * BB + b) * FS + part * 4;
            __builtin_amdgcn_global_load_lds(
                (const __attribute__((address_space(1))) void*)gp,
                (__attribute__((address_space(3))) void*)(rows + c * 4),
                16, 0, 0);
        }
    }
    __syncthreads();   // drains vmcnt: all chunks + sW/sv landed

    // ---- compute phase, thread = (nb_local, h) ----
    int lane = tid & 63, w = tid >> 6;
    int nbl  = w * 16 + (lane >> 2);     // 0..63
    int h    = lane & 3;
    int g    = nbl >> 5;                 // wave-uniform (w<2 -> 0, w>=2 -> 1)
    int b    = nbl & 31;
    int n    = n0 + g;
    int nb   = n * BB + b;
    int dg   = cfg.deg[n];

    float vl[TT];
#pragma unroll
    for (int t = 0; t < TT; t++) vl[t] = sv[h * TT + t];

    const float* selfrow = rows + ((g * SLOTS + 8) * 32 + b) * FS;
    float er = 0.f;
#pragma unroll
    for (int t = 0; t < TT; t++) er += sv[HH * TT + h * TT + t] * selfrow[t];

    float acc[TT];
#pragma unroll
    for (int t = 0; t < TT; t++) acc[t] = 0.f;
    float den = 0.f;

#pragma unroll
    for (int j = 0; j < JJ; j++) {
        const float* r = rows + ((g * SLOTS + j) * 32 + b) * FS;
        float fr[TT];
#pragma unroll
        for (int t = 0; t < TT; t++) fr[t] = r[t];
        float el = 0.f;
#pragma unroll
        for (int t = 0; t < TT; t++) el += vl[t] * fr[t];
        float z = el + er; z = (z >= 0.f) ? z : NEG * z;
        float wgt = __expf(z);
        wgt = (j < dg) ? wgt : 0.f;
        den += wgt;
#pragma unroll
        for (int t = 0; t < TT; t++) acc[t] += wgt * fr[t];
    }

    // overflow for deg > 8 (wave-uniform branch; ~2% of nodes)
    if (dg > JJ) {
        int off0 = cfg.off[n];
        for (int k = off0 + JJ; k < off0 + dg; k++) {
            int s = cfg.csr[k];
            float fr[TT];
            LOAD_ROW(fr, f + (size_t)(s * BB + b) * FS);
            float el = 0.f;
#pragma unroll
            for (int t = 0; t < TT; t++) el += vl[t] * fr[t];
            float z = el + er; z = (z >= 0.f) ? z : NEG * z;
            float wgt = __expf(z);
            den += wgt;
#pragma unroll
            for (int t = 0; t < TT; t++) acc[t] += wgt * fr[t];
        }
    }

    float rd = (dg > 0) ? (1.0f / den) : 0.f;

    // W_h on aggregated feat, leaky, mean over heads via shfl_xor
    float outv[DD];
#pragma unroll
    for (int d = 0; d < DD; d++) {
        float va = 0.f;
#pragma unroll
        for (int t = 0; t < TT; t++) va += sW[(h * DD + d) * TT + t] * acc[t];
        va *= rd;
        va = (va >= 0.f) ? va : NEG * va;
        outv[d] = va * 0.25f;
    }
#pragma unroll
    for (int d = 0; d < DD; d++) {
        outv[d] += __shfl_xor(outv[d], 1, 64);
        outv[d] += __shfl_xor(outv[d], 2, 64);
    }
    float lsum = 0.f, lsq = 0.f;
    if (h == 0) {
        float* gp = cfg.g + (size_t)nb * DD;
#pragma unroll
        for (int d = 0; d < DD; d++) {
            float o = outv[d];
            gp[d] = o;
            if (STATS) { lsum += o; lsq += o * o; }
        }
    }
    if (STATS) {
#pragma unroll
        for (int o = 32; o > 0; o >>= 1) {
            lsum += __shfl_down(lsum, o, 64);
            lsq  += __shfl_down(lsq, o, 64);
        }
        __shared__ float ss[4][2];
        if (lane == 0) { ss[w][0] = lsum; ss[w][1] = lsq; }
        __syncthreads();
        if (tid == 0) {
            float a0 = 0.f, a1 = 0.f;
#pragma unroll
            for (int q = 0; q < 4; q++) { a0 += ss[q][0]; a1 += ss[q][1]; }
            atomicAdd(&cfg.stats[0], a0);
            atomicAdd(&cfg.stats[1], a1);
        }
    }
}

// ---------------- LN(A), LN(B), average; writes padded feat rows ----------
__global__ void lncomb_kernel(const float* __restrict__ ga, const float* __restrict__ gb,
                              const float* __restrict__ stats, float* __restrict__ h) {
    int i = blockIdx.x * blockDim.x + threadIdx.x;
    if (i >= NBT) return;
    const float M = (float)NBT;
    float ma = stats[0] / M; float va = stats[1] / M - ma * ma;
    float mb = stats[2] / M; float vb = stats[3] / M - mb * mb;
    float ra = rsqrtf(va + 1e-5f), rb = rsqrtf(vb + 1e-5f);
    int nb = i / DD, t = i - nb * DD;
    h[(size_t)nb * FS + t] = 0.5f * ((ga[i] - ma) * ra + (gb[i] - mb) * rb);
}

// ---------------- final combine ----------------
__global__ void outcomb_kernel(const float* __restrict__ reg, const float* __restrict__ ga,
                               const float* __restrict__ gb, float* __restrict__ out) {
    int i = blockIdx.x * blockDim.x + threadIdx.x;
    if (i >= NBT) return;
    int nb = i / DD;
    out[i] = (reg[nb] + ga[i] + gb[i]) * (1.0f / 3.0f);
}

extern "C" void kernel_launch(void* const* d_in, const int* in_sizes, int n_in,
                              void* d_out, int out_size, void* d_ws, size_t ws_size,
                              hipStream_t stream) {
    const float* x      = (const float*)d_in[0];
    const int* ps_src   = (const int*)d_in[1];
    const int* ps_dst   = (const int*)d_in[2];
    const int* rl_src   = (const int*)d_in[3];
    const int* rl_dst   = (const int*)d_in[4];
    const float* mu_p_fc = (const float*)d_in[5];
    const float* mu_p_al = (const float*)d_in[6];
    const float* mu_p_ar = (const float*)d_in[7];
    const float* sg_p_fc = (const float*)d_in[8];
    const float* sg_p_al = (const float*)d_in[9];
    const float* sg_p_ar = (const float*)d_in[10];
    const float* mu_r_fc = (const float*)d_in[11];
    const float* mu_r_al = (const float*)d_in[12];
    const float* mu_r_ar = (const float*)d_in[13];
    const float* sg_r_fc = (const float*)d_in[14];
    const float* sg_r_al = (const float*)d_in[15];
    const float* sg_r_ar = (const float*)d_in[16];
    const float* reg_mu_w = (const float*)d_in[17];
    const float* reg_mu_b = (const float*)d_in[18];
    const float* reg_sg_w = (const float*)d_in[19];
    const float* reg_sg_b = (const float*)d_in[20];

    float* out = (float*)d_out;

    // ---- workspace carve ----
    float* fw = (float*)d_ws;
    float* mu    = fw;              fw += NBF;   // padded stride-12 feats
    float* sigma = fw;              fw += NBF;
    float* hp    = fw;              fw += NBF;
    float* hrl   = fw;              fw += NBF;
    float* gA    = fw;              fw += NBT;   // stride-10 GAT outputs
    float* gB    = fw;              fw += NBT;
    float* gA2   = fw;              fw += NBT;
    float* gB2   = fw;              fw += NBT;
    float* regmu = fw;              fw += NB;
    float* regsg = fw;              fw += NB;
    float* vbuf  = fw;              fw += 8 * 80;
    int* iw = (int*)fw;
    int* ps_off = iw;               iw += NN + 1;
    int* rl_off = iw;               iw += NN + 1;
    int* ps_csr = iw;               iw += EE;
    int* rl_csr = iw;               iw += EE;
    int* ps_c8  = iw;               iw += NN * JJ;
    int* rl_c8  = iw;               iw += NN * JJ;
    // zero region starts here:
    int* deg_ps = iw;               iw += NN;
    int* cur_ps = iw;               iw += NN;
    int* deg_rl = iw;               iw += NN;
    int* cur_rl = iw;               iw += NN;
    float* stats = (float*)iw;      // 8 floats
    size_t zero_bytes = (size_t)(4 * NN) * sizeof(int) + 8 * sizeof(float);
    hipMemsetAsync(deg_ps, 0, zero_bytes, stream);

    const int TPB = 256;
    const int GRID_NB  = (NB + TPB - 1) / TPB;
    const int GRID_NBT = (NBT + TPB - 1) / TPB;
    const int GRID_E   = (EE + TPB - 1) / TPB;
    const int GRID_C8  = (NN * JJ + TPB - 1) / TPB;

    extract_kernel<<<GRID_NB, TPB, 0, stream>>>(x, reg_mu_w, reg_mu_b, reg_sg_w, reg_sg_b,
                                                mu, sigma, regmu, regsg);

    // CSR (+padded csrP) for both graphs
    deg_kernel<<<GRID_E, TPB, 0, stream>>>(ps_dst, deg_ps);
    deg_kernel<<<GRID_E, TPB, 0, stream>>>(rl_dst, deg_rl);
    csr8init_kernel<<<GRID_C8, TPB, 0, stream>>>(ps_c8, rl_c8);
    scan_kernel<<<1, 1024, 0, stream>>>(deg_ps, ps_off);
    scan_kernel<<<1, 1024, 0, stream>>>(deg_rl, rl_off);
    fill_kernel<<<GRID_E, TPB, 0, stream>>>(ps_src, ps_dst, ps_off, cur_ps, ps_csr, ps_c8);
    fill_kernel<<<GRID_E, TPB, 0, stream>>>(rl_src, rl_dst, rl_off, cur_rl, rl_csr, rl_c8);

    // vl/vr precompute for all 8 GAT slots
    vpre_kernel<<<1, 320, 0, stream>>>(mu_p_fc, mu_p_al, mu_p_ar,
                                       sg_p_fc, sg_p_al, sg_p_ar,
                                       mu_r_fc, mu_r_al, mu_r_ar,
                                       sg_r_fc, sg_r_al, sg_r_ar, vbuf);

    // slots: 0 mu_p L0, 1 sg_p L0, 2 mu_r L0, 3 sg_r L0, 4 mu_p L1, 5 sg_p L1, 6 mu_r L1, 7 sg_r L1
    // ---- layer 0: 4 GAT passes, one dispatch (grid.y=4) ----
    {
        GatCfg4 c;
        c.c[0] = { mu,    mu_p_fc, vbuf + 0 * 80, ps_off, ps_csr, ps_c8, deg_ps, gA,  stats + 0 };
        c.c[1] = { sigma, sg_p_fc, vbuf + 1 * 80, ps_off, ps_csr, ps_c8, deg_ps, gB,  stats + 2 };
        c.c[2] = { mu,    mu_r_fc, vbuf + 2 * 80, rl_off, rl_csr, rl_c8, deg_rl, gA2, stats + 4 };
        c.c[3] = { sigma, sg_r_fc, vbuf + 3 * 80, rl_off, rl_csr, rl_c8, deg_rl, gB2, stats + 6 };
        dim3 grid(NN / 2, 4, 1);
        gatlds_kernel<true><<<grid, TPB, 0, stream>>>(c);
    }
    lncomb_kernel<<<GRID_NBT, TPB, 0, stream>>>(gA, gB, stats + 0, hp);
    lncomb_kernel<<<GRID_NBT, TPB, 0, stream>>>(gA2, gB2, stats + 4, hrl);

    // ---- final layers: 4 GAT passes, one dispatch ----
    {
        GatCfg4 c;
        c.c[0] = { hp,  mu_p_fc + 400, vbuf + 4 * 80, ps_off, ps_csr, ps_c8, deg_ps, gA,  nullptr };
        c.c[1] = { hp,  sg_p_fc + 400, vbuf + 5 * 80, ps_off, ps_csr, ps_c8, deg_ps, gB,  nullptr };
        c.c[2] = { hrl, mu_r_fc + 400, vbuf + 6 * 80, rl_off, rl_csr, rl_c8, deg_rl, gA2, nullptr };
        c.c[3] = { hrl, sg_r_fc + 400, vbuf + 7 * 80, rl_off, rl_csr, rl_c8, deg_rl, gB2, nullptr };
        dim3 grid(NN / 2, 4, 1);
        gatlds_kernel<false><<<grid, TPB, 0, stream>>>(c);
    }

    outcomb_kernel<<<GRID_NBT, TPB, 0, stream>>>(regmu, gA, gA2, out);
    outcomb_kernel<<<GRID_NBT, TPB, 0, stream>>>(regsg, gB, gB2, out + NBT);
}